// Round 5
// baseline (523.100 us; speedup 1.0000x reference)
//
#include <hip/hip_runtime.h>

#define NROWS 8192
#define DIM 512
#define HID 1024
#define BN_EPS 1e-5f

typedef unsigned short ushort_t;
typedef __attribute__((ext_vector_type(8))) __bf16 bf16x8;
typedef __attribute__((ext_vector_type(4))) float f32x4;

typedef __attribute__((address_space(3))) void lds_void_t;
typedef const __attribute__((address_space(1))) void gbl_void_t;

#define GLDS16(g, l) __builtin_amdgcn_global_load_lds((gbl_void_t*)(g), (lds_void_t*)(l), 16, 0, 0)

union U4 {
    uint4 u;
    bf16x8 b;
    ushort_t s[8];
};

static __device__ __forceinline__ float b2f(ushort_t u) {
    union { float f; unsigned int i; } c;
    c.i = ((unsigned int)u) << 16;
    return c.f;
}

static __device__ __forceinline__ ushort_t f2b(float f) {
    union { float f; unsigned int i; } c;
    c.f = f;
    unsigned int i = c.i;
    unsigned int r = (i + 0x7FFFu + ((i >> 16) & 1u)) >> 16;
    return (ushort_t)r;
}

// ---------------------------------------------------------------------------
// 1) colsum + convert: hs[d] += sum_n h[n,d]; hB = bf16(h).
// grid 256 x 256; each block covers 32 rows. hs pre-zeroed by memset.
__global__ void colsum_convert_kernel(const float* __restrict__ h, float* __restrict__ hs,
                                      ushort_t* __restrict__ hB) {
    int t = threadIdx.x;
    int col0 = (t & 127) * 4;
    int rsub = t >> 7;
    int row0 = blockIdx.x * 32;
    float acc[4] = {0.f, 0.f, 0.f, 0.f};
    for (int r = 0; r < 16; ++r) {
        int row = row0 + r * 2 + rsub;
        float4 v = *(const float4*)(h + (size_t)row * DIM + col0);
        acc[0] += v.x; acc[1] += v.y; acc[2] += v.z; acc[3] += v.w;
        ushort_t bv[4];
        bv[0] = f2b(v.x); bv[1] = f2b(v.y); bv[2] = f2b(v.z); bv[3] = f2b(v.w);
        *(uint2*)(hB + (size_t)row * DIM + col0) = *(uint2*)bv;
    }
#pragma unroll
    for (int j = 0; j < 4; ++j) atomicAdd(&hs[col0 + j], acc[j]);
}

// ---------------------------------------------------------------------------
// 2) fused scalar chain (1 block x 512):
//    s = hs@vw + 8192*vb;  t = s@ow + ob;
//    a1 = g1*rsqrt(v1+eps); q0 = t*a1 + (b1 - m1*a1);
//    a2 = g2*rsqrt(v2+eps); c2 = b2 - m2*a2;
//    b1P = q0@f1w + f1b  (1024 cols, 2 per thread)
__global__ void small_fused_kernel(const float* __restrict__ hs,
                                   const float* __restrict__ vw, const float* __restrict__ vb,
                                   const float* __restrict__ ow, const float* __restrict__ ob,
                                   const float* __restrict__ f1w, const float* __restrict__ f1b,
                                   const float* __restrict__ g1, const float* __restrict__ b1,
                                   const float* __restrict__ m1, const float* __restrict__ v1,
                                   const float* __restrict__ g2, const float* __restrict__ b2,
                                   const float* __restrict__ m2, const float* __restrict__ v2,
                                   float* __restrict__ cA1, float* __restrict__ cQ0,
                                   float* __restrict__ cA2, float* __restrict__ cC2,
                                   float* __restrict__ b1P) {
    __shared__ float sh[512];
    int t = threadIdx.x;
    float acc = 8192.0f * vb[t];
    for (int k = 0; k < 512; ++k) acc += hs[k] * vw[(size_t)k * 512 + t];
    sh[t] = acc;
    __syncthreads();
    float acc2 = ob[t];
    for (int k = 0; k < 512; ++k) acc2 += sh[k] * ow[(size_t)k * 512 + t];
    float a1 = g1[t] * rsqrtf(v1[t] + BN_EPS);
    float q0 = acc2 * a1 + (b1[t] - m1[t] * a1);
    float a2 = g2[t] * rsqrtf(v2[t] + BN_EPS);
    cA1[t] = a1;
    cQ0[t] = q0;
    cA2[t] = a2;
    cC2[t] = b2[t] - m2[t] * a2;
    __syncthreads();
    sh[t] = q0;
    __syncthreads();
#pragma unroll
    for (int c = t; c < 1024; c += 512) {
        float a = f1b[c];
        for (int k = 0; k < 512; ++k) a += sh[k] * f1w[(size_t)k * HID + c];
        b1P[c] = a;
    }
}

// ---------------------------------------------------------------------------
// 3) combined weight prep (1024 blocks x 256):
//  b < 512 : W1T[c][r] = bf16(f1w[r][c] * a1[r]),  f1w [512][1024]
//  b >= 512: W2T[c][r] = bf16(f2w[r][c]),          f2w [1024][512]
__global__ void prepw_kernel(const float* __restrict__ f1w,
                             const float* __restrict__ g1, const float* __restrict__ v1,
                             const float* __restrict__ f2w,
                             ushort_t* __restrict__ W1T, ushort_t* __restrict__ W2T) {
    __shared__ float tile[32][33];
    int tx = threadIdx.x & 31, ty = threadIdx.x >> 5;
    int b = blockIdx.x;
    if (b < 512) {
        int bx = (b & 31) * 32, by = (b >> 5) * 32;
#pragma unroll
        for (int i = 0; i < 32; i += 8)
            tile[ty + i][tx] = f1w[(size_t)(by + ty + i) * HID + bx + tx];
        __syncthreads();
        int r = by + tx;
        float a1 = g1[r] * rsqrtf(v1[r] + BN_EPS);
#pragma unroll
        for (int i = 0; i < 32; i += 8)
            W1T[(size_t)(bx + ty + i) * DIM + r] = f2b(tile[tx][ty + i] * a1);
    } else {
        int b2 = b - 512;
        int bx = (b2 & 15) * 32, by = (b2 >> 4) * 32;
#pragma unroll
        for (int i = 0; i < 32; i += 8)
            tile[ty + i][tx] = f2w[(size_t)(by + ty + i) * DIM + bx + tx];
        __syncthreads();
#pragma unroll
        for (int i = 0; i < 32; i += 8)
            W2T[(size_t)(bx + ty + i) * HID + by + tx] = f2b(tile[tx][ty + i]);
    }
}

// ---------------------------------------------------------------------------
// 4) GEMM1: Z = relu(hB @ W1T^T + b1P).  128x128 tile, BK=64, global_load_lds
// staging (unpadded LDS, XOR chunk swizzle c^=row&7 -> 2-way-free ds_read).
// 256 threads = 4 waves (2x2 of 64x64), each wave 4x4 of 16x16x32 MFMA,
// 2 k-substeps per tile = 32 MFMA per barrier.
__global__ __launch_bounds__(256) void gemm1_kernel(const ushort_t* __restrict__ A,
                                                    const ushort_t* __restrict__ BT,
                                                    const float* __restrict__ bias,
                                                    ushort_t* __restrict__ C) {
    const int K = DIM, Nn = HID;
    __shared__ ushort_t As[128 * 64];  // 16 KB, row stride 64 elem (128 B)
    __shared__ ushort_t Bs[128 * 64];  // 16 KB
    int tid = threadIdx.x;
    int lane = tid & 63, w = tid >> 6;
    int wm = (w & 1) * 64, wn = (w >> 1) * 64;
    int bm = blockIdx.y * 128, bn = blockIdx.x * 128;

    f32x4 acc[4][4] = {};

    int rsub = tid >> 3;                 // 0..31
    int clog = (tid & 7) ^ (rsub & 7);   // logical k-chunk this lane fetches
    int gcol = clog * 8;                 // element offset within k-tile

    for (int k0 = 0; k0 < K; k0 += 64) {
        __syncthreads();
#pragma unroll
        for (int R = 0; R < 4; ++R) {
            int row = R * 32 + rsub;
            GLDS16(A + (size_t)(bm + row) * K + k0 + gcol, As + (R * 256 + w * 64) * 8);
        }
#pragma unroll
        for (int R = 0; R < 4; ++R) {
            int row = R * 32 + rsub;
            GLDS16(BT + (size_t)(bn + row) * K + k0 + gcol, Bs + (R * 256 + w * 64) * 8);
        }
        __syncthreads();

#pragma unroll
        for (int s = 0; s < 2; ++s) {
            int cl = (lane >> 4) + s * 4;
            bf16x8 af[4], bfr[4];
#pragma unroll
            for (int i = 0; i < 4; ++i) {
                int row = wm + i * 16 + (lane & 15);
                int cp = cl ^ (row & 7);
                U4 tt; tt.u = *(const uint4*)(As + row * 64 + cp * 8);
                af[i] = tt.b;
            }
#pragma unroll
            for (int j = 0; j < 4; ++j) {
                int row = wn + j * 16 + (lane & 15);
                int cp = cl ^ (row & 7);
                U4 tt; tt.u = *(const uint4*)(Bs + row * 64 + cp * 8);
                bfr[j] = tt.b;
            }
#pragma unroll
            for (int i = 0; i < 4; ++i)
#pragma unroll
                for (int j = 0; j < 4; ++j)
                    acc[i][j] = __builtin_amdgcn_mfma_f32_16x16x32_bf16(af[i], bfr[j], acc[i][j], 0, 0, 0);
        }
    }

    // epilogue: D layout row=(lane>>4)*4+r, col=lane&15 (m91-verified)
#pragma unroll
    for (int i = 0; i < 4; ++i) {
        int row0 = bm + wm + i * 16 + (lane >> 4) * 4;
#pragma unroll
        for (int j = 0; j < 4; ++j) {
            int col = bn + wn + j * 16 + (lane & 15);
            float bv = bias[col];
#pragma unroll
            for (int r = 0; r < 4; ++r) {
                float v = fmaxf(acc[i][j][r] + bv, 0.f);
                C[(size_t)(row0 + r) * Nn + col] = f2b(v);
            }
        }
    }
}

// ---------------------------------------------------------------------------
// 5) GEMM2 + fused epilogue:
// out = ((hB*a1 + q0) + (Z @ W2T^T) + fb2) * a2 + c2.
// 128x64 tile, BK=64, global_load_lds staging, 4 waves (2x2 of 64x32).
__global__ __launch_bounds__(256) void gemm2_kernel(const ushort_t* __restrict__ A,
                                                    const ushort_t* __restrict__ BT,
                                                    const float* __restrict__ bias,
                                                    const ushort_t* __restrict__ hB,
                                                    const float* __restrict__ cA1,
                                                    const float* __restrict__ cQ0,
                                                    const float* __restrict__ cA2,
                                                    const float* __restrict__ cC2,
                                                    float* __restrict__ out) {
    const int K = HID;
    __shared__ ushort_t As[128 * 64];  // 16 KB
    __shared__ ushort_t Bs[64 * 64];   // 8 KB
    int tid = threadIdx.x;
    int lane = tid & 63, w = tid >> 6;
    int wm = (w & 1) * 64, wn = (w >> 1) * 32;
    int bm = blockIdx.y * 128, bn = blockIdx.x * 64;

    f32x4 acc[4][2] = {};

    int rsub = tid >> 3;
    int clog = (tid & 7) ^ (rsub & 7);
    int gcol = clog * 8;

    for (int k0 = 0; k0 < K; k0 += 64) {
        __syncthreads();
#pragma unroll
        for (int R = 0; R < 4; ++R) {
            int row = R * 32 + rsub;
            GLDS16(A + (size_t)(bm + row) * K + k0 + gcol, As + (R * 256 + w * 64) * 8);
        }
#pragma unroll
        for (int R = 0; R < 2; ++R) {
            int row = R * 32 + rsub;
            GLDS16(BT + (size_t)(bn + row) * K + k0 + gcol, Bs + (R * 256 + w * 64) * 8);
        }
        __syncthreads();

#pragma unroll
        for (int s = 0; s < 2; ++s) {
            int cl = (lane >> 4) + s * 4;
            bf16x8 af[4], bfr[2];
#pragma unroll
            for (int i = 0; i < 4; ++i) {
                int row = wm + i * 16 + (lane & 15);
                int cp = cl ^ (row & 7);
                U4 tt; tt.u = *(const uint4*)(As + row * 64 + cp * 8);
                af[i] = tt.b;
            }
#pragma unroll
            for (int j = 0; j < 2; ++j) {
                int row = wn + j * 16 + (lane & 15);
                int cp = cl ^ (row & 7);
                U4 tt; tt.u = *(const uint4*)(Bs + row * 64 + cp * 8);
                bfr[j] = tt.b;
            }
#pragma unroll
            for (int i = 0; i < 4; ++i)
#pragma unroll
                for (int j = 0; j < 2; ++j)
                    acc[i][j] = __builtin_amdgcn_mfma_f32_16x16x32_bf16(af[i], bfr[j], acc[i][j], 0, 0, 0);
        }
    }

#pragma unroll
    for (int i = 0; i < 4; ++i) {
        int row0 = bm + wm + i * 16 + (lane >> 4) * 4;
#pragma unroll
        for (int j = 0; j < 2; ++j) {
            int col = bn + wn + j * 16 + (lane & 15);
            float a1c = cA1[col], q0c = cQ0[col];
            float a2c = cA2[col], c2c = cC2[col];
            float bv = bias[col];
#pragma unroll
            for (int r = 0; r < 4; ++r) {
                int row = row0 + r;
                float x1 = b2f(hB[(size_t)row * DIM + col]) * a1c + q0c;
                out[(size_t)row * DIM + col] = (x1 + acc[i][j][r] + bv) * a2c + c2c;
            }
        }
    }
}

// ---------------------------------------------------------------------------
extern "C" void kernel_launch(void* const* d_in, const int* in_sizes, int n_in,
                              void* d_out, int out_size, void* d_ws, size_t ws_size,
                              hipStream_t stream) {
    // inputs (all fp32): 0:A 1:h 2:qw 3:qb 4:kw 5:kb 6:vw 7:vb 8:ow 9:ob
    // 10:f1w 11:f1b 12:f2w 13:f2b 14-17:bn1 g,b,m,v 18-21:bn2 g,b,m,v
    const float* h = (const float*)d_in[1];
    const float* vw = (const float*)d_in[6];
    const float* vb = (const float*)d_in[7];
    const float* ow = (const float*)d_in[8];
    const float* ob = (const float*)d_in[9];
    const float* f1w = (const float*)d_in[10];
    const float* f1b = (const float*)d_in[11];
    const float* f2w = (const float*)d_in[12];
    const float* fb2 = (const float*)d_in[13];
    const float* g1 = (const float*)d_in[14];
    const float* b1 = (const float*)d_in[15];
    const float* m1 = (const float*)d_in[16];
    const float* v1 = (const float*)d_in[17];
    const float* g2 = (const float*)d_in[18];
    const float* b2 = (const float*)d_in[19];
    const float* m2 = (const float*)d_in[20];
    const float* v2 = (const float*)d_in[21];
    float* out = (float*)d_out;

    char* ws = (char*)d_ws;
    float* hs = (float*)(ws + 0);          // 512 f32
    float* cA1 = (float*)(ws + 4096);      // 512 f32
    float* cQ0 = (float*)(ws + 6144);      // 512 f32
    float* cA2 = (float*)(ws + 8192);      // 512 f32
    float* cC2 = (float*)(ws + 10240);     // 512 f32
    float* b1P = (float*)(ws + 16384);     // 1024 f32
    ushort_t* W1T = (ushort_t*)(ws + 32768);               // [1024][512] bf16, 1 MB
    ushort_t* W2T = (ushort_t*)(ws + 32768 + 1048576);     // [512][1024] bf16, 1 MB
    ushort_t* Z = (ushort_t*)(ws + 32768 + 2097152);       // [8192][1024] bf16, 16 MB
    ushort_t* hB = (ushort_t*)(ws + 32768 + 2097152 + 16777216); // [8192][512] bf16, 8 MB

    hipMemsetAsync(hs, 0, 512 * sizeof(float), stream);
    colsum_convert_kernel<<<256, 256, 0, stream>>>(h, hs, hB);
    small_fused_kernel<<<1, 512, 0, stream>>>(hs, vw, vb, ow, ob, f1w, f1b,
                                              g1, b1, m1, v1, g2, b2, m2, v2,
                                              cA1, cQ0, cA2, cC2, b1P);
    prepw_kernel<<<1024, 256, 0, stream>>>(f1w, g1, v1, f2w, W1T, W2T);
    gemm1_kernel<<<dim3(8, 64), 256, 0, stream>>>(hB, W1T, b1P, Z);
    gemm2_kernel<<<dim3(8, 64), 256, 0, stream>>>(Z, W2T, fb2, hB, cA1, cQ0, cA2, cC2, out);
}

// Round 6
// 460.382 us; speedup vs baseline: 1.1362x; 1.1362x over previous
//
#include <hip/hip_runtime.h>

#define NROWS 8192
#define DIM 512
#define HID 1024
#define BN_EPS 1e-5f

typedef unsigned short ushort_t;
typedef __attribute__((ext_vector_type(8))) __bf16 bf16x8;
typedef __attribute__((ext_vector_type(4))) float f32x4;

union U4 {
    uint4 u;
    bf16x8 b;
    ushort_t s[8];
};

static __device__ __forceinline__ float b2f(ushort_t u) {
    union { float f; unsigned int i; } c;
    c.i = ((unsigned int)u) << 16;
    return c.f;
}

static __device__ __forceinline__ ushort_t f2b(float f) {
    union { float f; unsigned int i; } c;
    c.f = f;
    unsigned int i = c.i;
    unsigned int r = (i + 0x7FFFu + ((i >> 16) & 1u)) >> 16;
    return (ushort_t)r;
}

// ---------------------------------------------------------------------------
// 1) merged: blocks 0..255  -> colsum+convert (hs[d] += sum_n h[n,d]; hB=bf16(h))
//            blocks 256..767 -> W1T[c][r] = bf16(f1w[r][c] * a1[r])
//            blocks 768..1279-> W2T[c][r] = bf16(f2w[r][c])
// hs pre-zeroed by memset.  grid 1280 x 256.
__global__ void prep_kernel(const float* __restrict__ h, float* __restrict__ hs,
                            ushort_t* __restrict__ hB,
                            const float* __restrict__ f1w,
                            const float* __restrict__ g1, const float* __restrict__ v1,
                            const float* __restrict__ f2w,
                            ushort_t* __restrict__ W1T, ushort_t* __restrict__ W2T) {
    __shared__ float tile[32][33];
    int bid = blockIdx.x;
    if (bid < 256) {
        int t = threadIdx.x;
        int col0 = (t & 127) * 4;
        int rsub = t >> 7;
        int row0 = bid * 32;
        float acc[4] = {0.f, 0.f, 0.f, 0.f};
        for (int r = 0; r < 16; ++r) {
            int row = row0 + r * 2 + rsub;
            float4 v = *(const float4*)(h + (size_t)row * DIM + col0);
            acc[0] += v.x; acc[1] += v.y; acc[2] += v.z; acc[3] += v.w;
            ushort_t bv[4];
            bv[0] = f2b(v.x); bv[1] = f2b(v.y); bv[2] = f2b(v.z); bv[3] = f2b(v.w);
            *(uint2*)(hB + (size_t)row * DIM + col0) = *(uint2*)bv;
        }
#pragma unroll
        for (int j = 0; j < 4; ++j) atomicAdd(&hs[col0 + j], acc[j]);
    } else if (bid < 768) {
        int b = bid - 256;
        int tx = threadIdx.x & 31, ty = threadIdx.x >> 5;
        int bx = (b & 31) * 32, by = (b >> 5) * 32;
#pragma unroll
        for (int i = 0; i < 32; i += 8)
            tile[ty + i][tx] = f1w[(size_t)(by + ty + i) * HID + bx + tx];
        __syncthreads();
        int r = by + tx;
        float a1 = g1[r] * rsqrtf(v1[r] + BN_EPS);
#pragma unroll
        for (int i = 0; i < 32; i += 8)
            W1T[(size_t)(bx + ty + i) * DIM + r] = f2b(tile[tx][ty + i] * a1);
    } else {
        int b2 = bid - 768;
        int tx = threadIdx.x & 31, ty = threadIdx.x >> 5;
        int bx = (b2 & 15) * 32, by = (b2 >> 4) * 32;
#pragma unroll
        for (int i = 0; i < 32; i += 8)
            tile[ty + i][tx] = f2w[(size_t)(by + ty + i) * DIM + bx + tx];
        __syncthreads();
#pragma unroll
        for (int i = 0; i < 32; i += 8)
            W2T[(size_t)(bx + ty + i) * HID + by + tx] = f2b(tile[tx][ty + i]);
    }
}

// ---------------------------------------------------------------------------
// 2) matvec: outv[col] = sum_{k<512} xin[k]*W[k*ncols+col] + scaleB*bvec[col]
// grid (ncols/32) x 256.
__global__ void matvec_kernel(const float* __restrict__ xin, const float* __restrict__ W,
                              const float* __restrict__ bvec, float scaleB,
                              float* __restrict__ outv, int ncols) {
    __shared__ float red[8][32];
    int t = threadIdx.x;
    int col = blockIdx.x * 32 + (t & 31);
    int ks = t >> 5;
    float s = 0.f;
    for (int ki = 0; ki < 64; ++ki) {
        int k = ks * 64 + ki;
        s += xin[k] * W[(size_t)k * ncols + col];
    }
    red[ks][t & 31] = s;
    __syncthreads();
    if (ks == 0) {
        float tot = scaleB * bvec[col];
#pragma unroll
        for (int r = 0; r < 8; ++r) tot += red[r][t & 31];
        outv[col] = tot;
    }
}

// ---------------------------------------------------------------------------
// 2b) b1P[col] = f1b[col] + sum_k q0[k]*f1w[k*1024+col],
//     q0[k] = t[k]*a1[k] + (b1[k] - m1[k]*a1[k]), a1 = g1*rsqrt(v1+eps).
// grid 32 x 256.
__global__ void matvec_b1p_kernel(const float* __restrict__ tvec,
                                  const float* __restrict__ g1, const float* __restrict__ b1,
                                  const float* __restrict__ m1, const float* __restrict__ v1,
                                  const float* __restrict__ W, const float* __restrict__ bvec,
                                  float* __restrict__ outv) {
    __shared__ float red[8][32];
    int t = threadIdx.x;
    int col = blockIdx.x * 32 + (t & 31);
    int ks = t >> 5;
    float s = 0.f;
    for (int ki = 0; ki < 64; ++ki) {
        int k = ks * 64 + ki;
        float a1 = g1[k] * rsqrtf(v1[k] + BN_EPS);
        float q0 = tvec[k] * a1 + (b1[k] - m1[k] * a1);
        s += q0 * W[(size_t)k * HID + col];
    }
    red[ks][t & 31] = s;
    __syncthreads();
    if (ks == 0) {
        float tot = bvec[col];
#pragma unroll
        for (int r = 0; r < 8; ++r) tot += red[r][t & 31];
        outv[col] = tot;
    }
}

// ---------------------------------------------------------------------------
// 3) GEMM1: Z = relu(hB @ W1T^T + b1P).  128x128 tile, BK=64 (32 MFMA/barrier),
// padded LDS (LDA=72), 256 threads = 4 waves (2x2 of 64x64), wave 4x4 MFMA.
__global__ __launch_bounds__(256) void gemm1_kernel(const ushort_t* __restrict__ A,
                                                    const ushort_t* __restrict__ BT,
                                                    const float* __restrict__ bias,
                                                    ushort_t* __restrict__ C) {
    const int K = DIM, Nn = HID, LDA = 72;
    __shared__ ushort_t As[128 * LDA];
    __shared__ ushort_t Bs[128 * LDA];
    int tid = threadIdx.x;
    int lane = tid & 63, w = tid >> 6;
    int wm = (w & 1) * 64, wn = (w >> 1) * 64;
    int bm = blockIdx.y * 128, bn = blockIdx.x * 128;

    f32x4 acc[4][4] = {};

    int r0 = tid >> 2, kc0 = (tid & 3) * 8;
    int r1 = r0 + 64;

    for (int k0 = 0; k0 < K; k0 += 64) {
        __syncthreads();
        uint4 a00 = *(const uint4*)(A + (size_t)(bm + r0) * K + k0 + kc0);
        uint4 a01 = *(const uint4*)(A + (size_t)(bm + r0) * K + k0 + kc0 + 32);
        uint4 a10 = *(const uint4*)(A + (size_t)(bm + r1) * K + k0 + kc0);
        uint4 a11 = *(const uint4*)(A + (size_t)(bm + r1) * K + k0 + kc0 + 32);
        uint4 b00 = *(const uint4*)(BT + (size_t)(bn + r0) * K + k0 + kc0);
        uint4 b01 = *(const uint4*)(BT + (size_t)(bn + r0) * K + k0 + kc0 + 32);
        uint4 b10 = *(const uint4*)(BT + (size_t)(bn + r1) * K + k0 + kc0);
        uint4 b11 = *(const uint4*)(BT + (size_t)(bn + r1) * K + k0 + kc0 + 32);
        *(uint4*)(As + r0 * LDA + kc0) = a00;
        *(uint4*)(As + r0 * LDA + kc0 + 32) = a01;
        *(uint4*)(As + r1 * LDA + kc0) = a10;
        *(uint4*)(As + r1 * LDA + kc0 + 32) = a11;
        *(uint4*)(Bs + r0 * LDA + kc0) = b00;
        *(uint4*)(Bs + r0 * LDA + kc0 + 32) = b01;
        *(uint4*)(Bs + r1 * LDA + kc0) = b10;
        *(uint4*)(Bs + r1 * LDA + kc0 + 32) = b11;
        __syncthreads();

#pragma unroll
        for (int s = 0; s < 2; ++s) {
            int koff = (lane >> 4) * 8 + s * 32;
            bf16x8 af[4], bfr[4];
#pragma unroll
            for (int i = 0; i < 4; ++i) {
                U4 t;
                t.u = *(const uint4*)(As + (wm + i * 16 + (lane & 15)) * LDA + koff);
                af[i] = t.b;
            }
#pragma unroll
            for (int j = 0; j < 4; ++j) {
                U4 t;
                t.u = *(const uint4*)(Bs + (wn + j * 16 + (lane & 15)) * LDA + koff);
                bfr[j] = t.b;
            }
#pragma unroll
            for (int i = 0; i < 4; ++i)
#pragma unroll
                for (int j = 0; j < 4; ++j)
                    acc[i][j] = __builtin_amdgcn_mfma_f32_16x16x32_bf16(af[i], bfr[j], acc[i][j], 0, 0, 0);
        }
    }

    // epilogue: D layout row=(lane>>4)*4+r, col=lane&15 (m91-verified)
#pragma unroll
    for (int i = 0; i < 4; ++i) {
        int row0 = bm + wm + i * 16 + (lane >> 4) * 4;
#pragma unroll
        for (int j = 0; j < 4; ++j) {
            int col = bn + wn + j * 16 + (lane & 15);
            float bv = bias[col];
#pragma unroll
            for (int r = 0; r < 4; ++r) {
                float v = fmaxf(acc[i][j][r] + bv, 0.f);
                C[(size_t)(row0 + r) * Nn + col] = f2b(v);
            }
        }
    }
}

// ---------------------------------------------------------------------------
// 4) GEMM2 + fused epilogue:
// out = ((hB*a1 + q0) + (Z @ W2T^T) + fb2) * a2 + c2,  consts inline.
// 128x64 tile, BK=64, padded LDS, 4 waves (2x2 of 64x32), grid (8, 64).
__global__ __launch_bounds__(256) void gemm2_kernel(const ushort_t* __restrict__ A,
                                                    const ushort_t* __restrict__ BT,
                                                    const float* __restrict__ bias,
                                                    const ushort_t* __restrict__ hB,
                                                    const float* __restrict__ tvec,
                                                    const float* __restrict__ g1,
                                                    const float* __restrict__ b1,
                                                    const float* __restrict__ m1,
                                                    const float* __restrict__ v1,
                                                    const float* __restrict__ g2,
                                                    const float* __restrict__ b2,
                                                    const float* __restrict__ m2,
                                                    const float* __restrict__ v2,
                                                    float* __restrict__ out) {
    const int K = HID, LDA = 72;
    __shared__ ushort_t As[128 * LDA];
    __shared__ ushort_t Bs[64 * LDA];
    int tid = threadIdx.x;
    int lane = tid & 63, w = tid >> 6;
    int wm = (w & 1) * 64, wn = (w >> 1) * 32;
    int bm = blockIdx.y * 128, bn = blockIdx.x * 64;

    f32x4 acc[4][2] = {};

    int r0 = tid >> 2, kc0 = (tid & 3) * 8;
    int r1 = r0 + 64;

    for (int k0 = 0; k0 < K; k0 += 64) {
        __syncthreads();
        uint4 a00 = *(const uint4*)(A + (size_t)(bm + r0) * K + k0 + kc0);
        uint4 a01 = *(const uint4*)(A + (size_t)(bm + r0) * K + k0 + kc0 + 32);
        uint4 a10 = *(const uint4*)(A + (size_t)(bm + r1) * K + k0 + kc0);
        uint4 a11 = *(const uint4*)(A + (size_t)(bm + r1) * K + k0 + kc0 + 32);
        uint4 b00 = *(const uint4*)(BT + (size_t)(bn + r0) * K + k0 + kc0);
        uint4 b01 = *(const uint4*)(BT + (size_t)(bn + r0) * K + k0 + kc0 + 32);
        *(uint4*)(As + r0 * LDA + kc0) = a00;
        *(uint4*)(As + r0 * LDA + kc0 + 32) = a01;
        *(uint4*)(As + r1 * LDA + kc0) = a10;
        *(uint4*)(As + r1 * LDA + kc0 + 32) = a11;
        *(uint4*)(Bs + r0 * LDA + kc0) = b00;
        *(uint4*)(Bs + r0 * LDA + kc0 + 32) = b01;
        __syncthreads();

#pragma unroll
        for (int s = 0; s < 2; ++s) {
            int koff = (lane >> 4) * 8 + s * 32;
            bf16x8 af[4], bfr[2];
#pragma unroll
            for (int i = 0; i < 4; ++i) {
                U4 t;
                t.u = *(const uint4*)(As + (wm + i * 16 + (lane & 15)) * LDA + koff);
                af[i] = t.b;
            }
#pragma unroll
            for (int j = 0; j < 2; ++j) {
                U4 t;
                t.u = *(const uint4*)(Bs + (wn + j * 16 + (lane & 15)) * LDA + koff);
                bfr[j] = t.b;
            }
#pragma unroll
            for (int i = 0; i < 4; ++i)
#pragma unroll
                for (int j = 0; j < 2; ++j)
                    acc[i][j] = __builtin_amdgcn_mfma_f32_16x16x32_bf16(af[i], bfr[j], acc[i][j], 0, 0, 0);
        }
    }

#pragma unroll
    for (int i = 0; i < 4; ++i) {
        int row0 = bm + wm + i * 16 + (lane >> 4) * 4;
#pragma unroll
        for (int j = 0; j < 2; ++j) {
            int col = bn + wn + j * 16 + (lane & 15);
            float a1c = g1[col] * rsqrtf(v1[col] + BN_EPS);
            float q0c = tvec[col] * a1c + (b1[col] - m1[col] * a1c);
            float a2c = g2[col] * rsqrtf(v2[col] + BN_EPS);
            float c2c = b2[col] - m2[col] * a2c;
            float bv = bias[col];
#pragma unroll
            for (int r = 0; r < 4; ++r) {
                int row = row0 + r;
                float x1 = b2f(hB[(size_t)row * DIM + col]) * a1c + q0c;
                out[(size_t)row * DIM + col] = (x1 + acc[i][j][r] + bv) * a2c + c2c;
            }
        }
    }
}

// ---------------------------------------------------------------------------
extern "C" void kernel_launch(void* const* d_in, const int* in_sizes, int n_in,
                              void* d_out, int out_size, void* d_ws, size_t ws_size,
                              hipStream_t stream) {
    // inputs (all fp32): 0:A 1:h 2:qw 3:qb 4:kw 5:kb 6:vw 7:vb 8:ow 9:ob
    // 10:f1w 11:f1b 12:f2w 13:f2b 14-17:bn1 g,b,m,v 18-21:bn2 g,b,m,v
    const float* h = (const float*)d_in[1];
    const float* vw = (const float*)d_in[6];
    const float* vb = (const float*)d_in[7];
    const float* ow = (const float*)d_in[8];
    const float* ob = (const float*)d_in[9];
    const float* f1w = (const float*)d_in[10];
    const float* f1b = (const float*)d_in[11];
    const float* f2w = (const float*)d_in[12];
    const float* fb2 = (const float*)d_in[13];
    const float* g1 = (const float*)d_in[14];
    const float* b1 = (const float*)d_in[15];
    const float* m1 = (const float*)d_in[16];
    const float* v1 = (const float*)d_in[17];
    const float* g2 = (const float*)d_in[18];
    const float* b2 = (const float*)d_in[19];
    const float* m2 = (const float*)d_in[20];
    const float* v2 = (const float*)d_in[21];
    float* out = (float*)d_out;

    char* ws = (char*)d_ws;
    float* hs = (float*)(ws + 0);          // 512 f32
    float* sBuf = (float*)(ws + 4096);     // 512 f32
    float* tBuf = (float*)(ws + 8192);     // 512 f32
    float* b1P = (float*)(ws + 16384);     // 1024 f32
    ushort_t* W1T = (ushort_t*)(ws + 32768);               // [1024][512] bf16, 1 MB
    ushort_t* W2T = (ushort_t*)(ws + 32768 + 1048576);     // [512][1024] bf16, 1 MB
    ushort_t* Z = (ushort_t*)(ws + 32768 + 2097152);       // [8192][1024] bf16, 16 MB
    ushort_t* hB = (ushort_t*)(ws + 32768 + 2097152 + 16777216); // [8192][512] bf16, 8 MB

    hipMemsetAsync(hs, 0, 512 * sizeof(float), stream);
    prep_kernel<<<1280, 256, 0, stream>>>(h, hs, hB, f1w, g1, v1, f2w, W1T, W2T);
    matvec_kernel<<<16, 256, 0, stream>>>(hs, vw, vb, 8192.0f, sBuf, 512);
    matvec_kernel<<<16, 256, 0, stream>>>(sBuf, ow, ob, 1.0f, tBuf, 512);
    matvec_b1p_kernel<<<32, 256, 0, stream>>>(tBuf, g1, b1, m1, v1, f1w, f1b, b1P);
    gemm1_kernel<<<dim3(8, 64), 256, 0, stream>>>(hB, W1T, b1P, Z);
    gemm2_kernel<<<dim3(8, 64), 256, 0, stream>>>(Z, W2T, fb2, hB, tBuf,
                                                  g1, b1, m1, v1, g2, b2, m2, v2, out);
}